// Round 3
// baseline (718.146 us; speedup 1.0000x reference)
//
#include <hip/hip_runtime.h>

#define N_NODES 10000
#define N_EDGES 320000
#define INV3 0.5773502691896258f

__device__ __forceinline__ float gelu_f(float x) {
    // jax.nn.gelu approximate=True
    float x3 = x * x * x;
    return x / (1.0f + __expf(-1.5957691216057308f * (x + 0.044715f * x3)));
}

// ---------------- CSR build ----------------
__global__ __launch_bounds__(256) void hist_kernel(const int* __restrict__ dst, int* __restrict__ deg) {
    int e = blockIdx.x * 256 + threadIdx.x;
    if (e < N_EDGES) atomicAdd(&deg[dst[e]], 1);
}

__global__ __launch_bounds__(256) void scan_kernel(const int* __restrict__ deg,
                                                   int* __restrict__ rowptr,
                                                   int* __restrict__ cursor) {
    __shared__ int part[256];
    const int t = threadIdx.x;
    const int base = t * 40;
    int s = 0;
    for (int i = 0; i < 40; ++i) {
        int idx = base + i;
        if (idx < N_NODES) s += deg[idx];
    }
    part[t] = s;
    __syncthreads();
    for (int o = 1; o < 256; o <<= 1) {
        int v = (t >= o) ? part[t - o] : 0;
        __syncthreads();
        part[t] += v;
        __syncthreads();
    }
    int run = (t == 0) ? 0 : part[t - 1];
    for (int i = 0; i < 40; ++i) {
        int idx = base + i;
        if (idx < N_NODES) {
            int d = deg[idx];
            rowptr[idx] = run;
            cursor[idx] = run;
            run += d;
        } else if (idx == N_NODES) {
            rowptr[idx] = run;
        }
    }
}

__global__ __launch_bounds__(256) void scatter_kernel(const int* __restrict__ dst,
                                                      int* __restrict__ cursor,
                                                      int* __restrict__ elist) {
    int e = blockIdx.x * 256 + threadIdx.x;
    if (e < N_EDGES) {
        int p = atomicAdd(&cursor[dst[e]], 1);
        elist[p] = e;
    }
}

// ---------------- Kernel A: per-node linear1 (f_s, f_v) ----------------
__global__ __launch_bounds__(64) void node_l1_kernel(
    const float* __restrict__ node_input,
    const float* __restrict__ node_attr,
    const float* __restrict__ Wl1_0,
    const float* __restrict__ Wl1_1,
    float* __restrict__ f_s,
    float* __restrict__ f_v)
{
    const int n = blockIdx.x;
    const int t = threadIdx.x;
    __shared__ float x[160];
    const float* row = node_input + (size_t)n * 160;
    for (int i = t; i < 160; i += 64) x[i] = row[i];
    __syncthreads();
    const float a = node_attr[n];

    float acc = 0.f;
    for (int k = 0; k < 64; ++k) acc += x[k] * Wl1_0[k * 64 + t];
    f_s[(size_t)n * 64 + t] = acc * (a * 0.125f);

    const float sv = a * 0.17677669529663687f;
    for (int o = t; o < 96; o += 64) {
        int w = o / 3, c = o - w * 3;
        float av = 0.f;
        for (int u = 0; u < 32; ++u) av += x[64 + u * 3 + c] * Wl1_1[u * 32 + w];
        f_v[(size_t)n * 96 + o] = av * sv;
    }
}

// ---------------- Kernel B: sorted edges, reg-resident MLP + TP + segmented scatter ----------------
#define SEGSTEP(v, a, m) { float u_ = __int_as_float(__builtin_amdgcn_ds_bpermute((a), __float_as_int(v))); (v) += u_ * (m); }
#define SEGSCAN(v) { SEGSTEP(v, a1, m1) SEGSTEP(v, a2, m2) SEGSTEP(v, a4, m4) SEGSTEP(v, a8, m8) SEGSTEP(v, a16, m16) SEGSTEP(v, a32, m32) }

#define W1OFF 0        // [8][64]
#define W2OFF 512      // [64][64]
#define W3OFF 4608     // [64][192]

__global__ __launch_bounds__(512, 4) void edge_kernel(
    const float* __restrict__ edge_attr,   // [E][4]
    const float* __restrict__ esa,         // [E][8]
    const float* __restrict__ Wfc1,        // [8][64]
    const float* __restrict__ Wfc2,        // [64][64]
    const float* __restrict__ Wfc3,        // [64][192]
    const float* __restrict__ f_s,         // [N][64]
    const float* __restrict__ f_v,         // [N][96]
    const int* __restrict__ edge_src,
    const int* __restrict__ edge_dst,
    const int* __restrict__ elist,         // dst-sorted edge ids
    float* __restrict__ mid)               // [N][384], pre-zeroed
{
    __shared__ float wlds[16896];          // 67584 B: all MLP weights
    const int tid = threadIdx.x;
    const int lane = tid & 63;

    for (int i = tid; i < 512; i += 512)   wlds[W1OFF + i] = Wfc1[i];
    for (int i = tid; i < 4096; i += 512)  wlds[W2OFF + i] = Wfc2[i];
    for (int i = tid; i < 12288; i += 512) wlds[W3OFF + i] = Wfc3[i];
    __syncthreads();

    const int s = blockIdx.x * 512 + tid;
    const int e = elist[s];

    float4 xa = ((const float4*)esa)[e * 2 + 0];
    float4 xb = ((const float4*)esa)[e * 2 + 1];
    float x[8] = {xa.x, xa.y, xa.z, xa.w, xb.x, xb.y, xb.z, xb.w};

    // ----- fused layer1 -> layer2, h2 in registers -----
    float h2[64];
    #pragma unroll
    for (int j = 0; j < 64; ++j) h2[j] = 0.f;
    #pragma unroll 1
    for (int kc = 0; kc < 4; ++kc) {
        float t[16];
        #pragma unroll
        for (int i = 0; i < 16; ++i) {
            float acc = 0.f;
            #pragma unroll
            for (int k = 0; k < 8; ++k) acc += x[k] * wlds[W1OFF + k * 64 + kc * 16 + i];
            t[i] = gelu_f(acc * 0.35355339059327373f);
        }
        #pragma unroll
        for (int i = 0; i < 16; ++i) {
            #pragma unroll
            for (int j = 0; j < 64; ++j)
                h2[j] += t[i] * wlds[W2OFF + (kc * 16 + i) * 64 + j];
        }
    }
    #pragma unroll
    for (int j = 0; j < 64; ++j) h2[j] = gelu_f(h2[j] * 0.125f);

    // per-edge data
    const int src = edge_src[e];
    const int mydst = edge_dst[e];
    float4 ea = ((const float4*)edge_attr)[e];
    const float y0 = ea.x, y1a = ea.y, y1b = ea.z, y1c = ea.w;
    const float* gsrow = f_s + (size_t)src * 64;
    const float* gvrow = f_v + (size_t)src * 96;
    float* md = mid + (size_t)mydst * 384;

    // ---- per-wave segment info (edges sorted by dst) ----
    int up = __shfl_up(mydst, 1);
    bool is_head = (lane == 0) || (up != mydst);
    int dn = __shfl_down(mydst, 1);
    const bool is_tail = (lane == 63) || (dn != mydst);
    unsigned long long hb = __ballot(is_head);
    unsigned long long lowmask = (~0ull) >> (63 - lane);
    int H = 63 - __clzll(hb & lowmask);
    int dist = lane - H;
    const float m1  = dist >= 1  ? 1.f : 0.f;
    const float m2  = dist >= 2  ? 1.f : 0.f;
    const float m4  = dist >= 4  ? 1.f : 0.f;
    const float m8  = dist >= 8  ? 1.f : 0.f;
    const float m16 = dist >= 16 ? 1.f : 0.f;
    const float m32 = dist >= 32 ? 1.f : 0.f;
    const int a1  = ((lane - 1)  & 63) * 4;
    const int a2  = ((lane - 2)  & 63) * 4;
    const int a4  = ((lane - 4)  & 63) * 4;
    const int a8  = ((lane - 8)  & 63) * 4;
    const int a16 = ((lane - 16) & 63) * 4;
    const int a32 = ((lane - 32) & 63) * 4;

    // ---- PASS A: w0 (cols 0..63) -> mid[0:64] = 0.125*w0*gs*y0 ----
    #pragma unroll 1
    for (int jg = 0; jg < 4; ++jg) {
        float acc[16];
        #pragma unroll
        for (int i = 0; i < 16; ++i) acc[i] = 0.f;
        const int wb = W3OFF + jg * 16;
        #pragma unroll
        for (int k = 0; k < 64; ++k) {
            #pragma unroll
            for (int i = 0; i < 16; ++i) acc[i] += h2[k] * wlds[wb + k * 192 + i];
        }
        float gs16[16];
        #pragma unroll
        for (int q = 0; q < 4; ++q) {
            float4 g = ((const float4*)(gsrow + jg * 16))[q];
            gs16[q * 4 + 0] = g.x; gs16[q * 4 + 1] = g.y;
            gs16[q * 4 + 2] = g.z; gs16[q * 4 + 3] = g.w;
        }
        #pragma unroll
        for (int i = 0; i < 16; ++i) {
            acc[i] = 0.125f * acc[i] * gs16[i] * y0;
            SEGSCAN(acc[i]);
        }
        if (is_tail) {
            #pragma unroll
            for (int i = 0; i < 16; ++i) atomicAdd(md + jg * 16 + i, acc[i]);
        }
    }

    // ---- PASS B: w1 (cols 64..127) -> mid[96 + u*3 + c] = 0.125*w1*gs*y1[c] ----
    #pragma unroll 1
    for (int jg = 0; jg < 8; ++jg) {
        float acc[8];
        #pragma unroll
        for (int i = 0; i < 8; ++i) acc[i] = 0.f;
        const int wb = W3OFF + 64 + jg * 8;
        #pragma unroll
        for (int k = 0; k < 64; ++k) {
            #pragma unroll
            for (int i = 0; i < 8; ++i) acc[i] += h2[k] * wlds[wb + k * 192 + i];
        }
        float gs8[8];
        #pragma unroll
        for (int q = 0; q < 2; ++q) {
            float4 g = ((const float4*)(gsrow + jg * 8))[q];
            gs8[q * 4 + 0] = g.x; gs8[q * 4 + 1] = g.y;
            gs8[q * 4 + 2] = g.z; gs8[q * 4 + 3] = g.w;
        }
        float vb[8], vc[8];
        #pragma unroll
        for (int i = 0; i < 8; ++i) {
            float tt = 0.125f * acc[i] * gs8[i];
            acc[i] = tt * y1a; vb[i] = tt * y1b; vc[i] = tt * y1c;
            SEGSCAN(acc[i]);
        }
        #pragma unroll
        for (int i = 0; i < 8; ++i) { SEGSCAN(vb[i]); }
        #pragma unroll
        for (int i = 0; i < 8; ++i) { SEGSCAN(vc[i]); }
        if (is_tail) {
            #pragma unroll
            for (int i = 0; i < 8; ++i) {
                int u = jg * 8 + i;
                atomicAdd(md + 96 + u * 3 + 0, acc[i]);
                atomicAdd(md + 96 + u * 3 + 1, vb[i]);
                atomicAdd(md + 96 + u * 3 + 2, vc[i]);
            }
        }
    }

    // ---- PASS C: w2 (cols 128..159) -> mid[288 + u*3 + c] = 0.125*w2*gv[u][c]*y0 ----
    #pragma unroll 1
    for (int jg = 0; jg < 4; ++jg) {
        float acc[8];
        #pragma unroll
        for (int i = 0; i < 8; ++i) acc[i] = 0.f;
        const int wb = W3OFF + 128 + jg * 8;
        #pragma unroll
        for (int k = 0; k < 64; ++k) {
            #pragma unroll
            for (int i = 0; i < 8; ++i) acc[i] += h2[k] * wlds[wb + k * 192 + i];
        }
        float vb[8], vc[8];
        #pragma unroll
        for (int i = 0; i < 8; ++i) {
            int u = jg * 8 + i;
            float w2v = 0.125f * acc[i] * y0;
            acc[i] = w2v * gvrow[u * 3 + 0];
            vb[i]  = w2v * gvrow[u * 3 + 1];
            vc[i]  = w2v * gvrow[u * 3 + 2];
            SEGSCAN(acc[i]);
        }
        #pragma unroll
        for (int i = 0; i < 8; ++i) { SEGSCAN(vb[i]); }
        #pragma unroll
        for (int i = 0; i < 8; ++i) { SEGSCAN(vc[i]); }
        if (is_tail) {
            #pragma unroll
            for (int i = 0; i < 8; ++i) {
                int u = jg * 8 + i;
                atomicAdd(md + 288 + u * 3 + 0, acc[i]);
                atomicAdd(md + 288 + u * 3 + 1, vb[i]);
                atomicAdd(md + 288 + u * 3 + 2, vc[i]);
            }
        }
    }

    // ---- PASS D: w3 (cols 160..191) -> mid[64 + u] = 0.125*w3*(gv[u].y1)*INV3 ----
    #pragma unroll 1
    for (int jg = 0; jg < 2; ++jg) {
        float acc[16];
        #pragma unroll
        for (int i = 0; i < 16; ++i) acc[i] = 0.f;
        const int wb = W3OFF + 160 + jg * 16;
        #pragma unroll
        for (int k = 0; k < 64; ++k) {
            #pragma unroll
            for (int i = 0; i < 16; ++i) acc[i] += h2[k] * wlds[wb + k * 192 + i];
        }
        #pragma unroll
        for (int i = 0; i < 16; ++i) {
            int u = jg * 16 + i;
            float dot = gvrow[u * 3 + 0] * y1a + gvrow[u * 3 + 1] * y1b + gvrow[u * 3 + 2] * y1c;
            acc[i] = 0.125f * acc[i] * dot * INV3;
            SEGSCAN(acc[i]);
        }
        if (is_tail) {
            #pragma unroll
            for (int i = 0; i < 16; ++i) atomicAdd(md + 64 + jg * 16 + i, acc[i]);
        }
    }
}

// ---------------- Kernel C: per-node linear2 + gate + self-connection ----------------
__global__ __launch_bounds__(64) void node_out_kernel(
    const float* __restrict__ node_input,
    const float* __restrict__ node_attr,
    const float* __restrict__ Wsc0,
    const float* __restrict__ Wsc1,
    const float* __restrict__ Wl2_s,
    const float* __restrict__ Wl2_v,
    const float* __restrict__ Wa,
    const float* __restrict__ mid,
    float* __restrict__ out)
{
    const int n = blockIdx.x;
    const int t = threadIdx.x;
    __shared__ float x[160];
    __shared__ float m[384];
    const float inv = 0.17677669529663687f;  // 1/sqrt(NUM_NEIGHBORS)
    const float* row = node_input + (size_t)n * 160;
    for (int i = t; i < 160; i += 64) x[i] = row[i];
    for (int i = t; i < 384; i += 64) m[i] = mid[(size_t)n * 384 + i] * inv;
    __syncthreads();

    const float a = node_attr[n];
    const float s96 = a * 0.10206207261596575f;

    float alpha = 0.f;
    for (int i = 0; i < 96; ++i) alpha += m[i] * Wa[i];
    alpha *= s96;

    float outs = 0.f;
    for (int i = 0; i < 96; ++i) outs += m[i] * Wl2_s[i * 64 + t];
    outs *= s96;
    float scs = 0.f;
    for (int k = 0; k < 64; ++k) scs += x[k] * Wsc0[k * 64 + t];
    scs *= a * 0.125f;
    out[(size_t)n * 160 + t] = scs + alpha * outs;

    const float sv = a * 0.17677669529663687f;
    for (int o = t; o < 96; o += 64) {
        int w = o / 3, c = o - w * 3;
        float ov = 0.f;
        for (int u = 0; u < 64; ++u) ov += m[96 + u * 3 + c] * Wl2_v[u * 32 + w];
        for (int u = 0; u < 32; ++u) ov += m[288 + u * 3 + c] * Wl2_v[(64 + u) * 32 + w];
        ov *= s96;
        float scv = 0.f;
        for (int u = 0; u < 32; ++u) scv += x[64 + u * 3 + c] * Wsc1[u * 32 + w];
        scv *= sv;
        out[(size_t)n * 160 + 64 + o] = scv + alpha * ov;
    }
}

extern "C" void kernel_launch(void* const* d_in, const int* in_sizes, int n_in,
                              void* d_out, int out_size, void* d_ws, size_t ws_size,
                              hipStream_t stream) {
    const float* node_input = (const float*)d_in[0];
    const float* node_attr  = (const float*)d_in[1];
    const float* edge_attr  = (const float*)d_in[2];
    const float* esa        = (const float*)d_in[3];
    const float* Wsc0       = (const float*)d_in[4];
    const float* Wsc1       = (const float*)d_in[5];
    const float* Wl1_0      = (const float*)d_in[6];
    const float* Wl1_1      = (const float*)d_in[7];
    const float* Wfc1       = (const float*)d_in[8];
    const float* Wfc2       = (const float*)d_in[9];
    const float* Wfc3       = (const float*)d_in[10];
    const float* Wl2_s      = (const float*)d_in[11];
    const float* Wl2_v      = (const float*)d_in[12];
    const float* Wa         = (const float*)d_in[13];
    const int* edge_src     = (const int*)d_in[14];
    const int* edge_dst     = (const int*)d_in[15];
    float* out = (float*)d_out;

    float* ws  = (float*)d_ws;
    float* f_s = ws;                          // N*64
    float* f_v = ws + (size_t)N_NODES * 64;   // N*96
    float* mid = ws + (size_t)N_NODES * 160;  // N*384

    // CSR scratch lives in d_out (dead until node_out_kernel overwrites it)
    int* ibuf   = (int*)d_out;
    int* deg    = ibuf;            // 10000
    int* rowptr = ibuf + 10016;    // 10001
    int* cursor = ibuf + 20032;    // 10000
    int* elist  = ibuf + 30080;    // 320000 -> end 350080 < 1.6M floats

    hipMemsetAsync(deg, 0, (size_t)N_NODES * sizeof(int), stream);
    hipMemsetAsync(mid, 0, (size_t)N_NODES * 384 * sizeof(float), stream);

    hist_kernel<<<(N_EDGES + 255) / 256, 256, 0, stream>>>(edge_dst, deg);
    scan_kernel<<<1, 256, 0, stream>>>(deg, rowptr, cursor);
    scatter_kernel<<<(N_EDGES + 255) / 256, 256, 0, stream>>>(edge_dst, cursor, elist);

    node_l1_kernel<<<N_NODES, 64, 0, stream>>>(node_input, node_attr, Wl1_0, Wl1_1, f_s, f_v);
    edge_kernel<<<N_EDGES / 512, 512, 0, stream>>>(edge_attr, esa, Wfc1, Wfc2, Wfc3,
                                                   f_s, f_v, edge_src, edge_dst, elist, mid);
    node_out_kernel<<<N_NODES, 64, 0, stream>>>(node_input, node_attr, Wsc0, Wsc1,
                                                Wl2_s, Wl2_v, Wa, mid, out);
}

// Round 4
// 525.390 us; speedup vs baseline: 1.3669x; 1.3669x over previous
//
#include <hip/hip_runtime.h>

#define N_NODES 10000
#define N_EDGES 320000
#define INV3 0.5773502691896258f

typedef short short8 __attribute__((ext_vector_type(8)));
typedef float f32x4 __attribute__((ext_vector_type(4)));

__device__ __forceinline__ float gelu_f(float x) {
    float x3 = x * x * x;
    return x / (1.0f + __expf(-1.5957691216057308f * (x + 0.044715f * x3)));
}

__device__ __forceinline__ unsigned short f2bf(float f) {
    unsigned u = __float_as_uint(f);
    unsigned r = (u + 0x7FFFu + ((u >> 16) & 1u)) >> 16;
    return (unsigned short)r;
}
__device__ __forceinline__ unsigned pk2(unsigned short lo, unsigned short hi) {
    return (unsigned)lo | ((unsigned)hi << 16);
}

// ---------------- CSR build ----------------
__global__ __launch_bounds__(256) void hist_kernel(const int* __restrict__ dst, int* __restrict__ deg) {
    int e = blockIdx.x * 256 + threadIdx.x;
    if (e < N_EDGES) atomicAdd(&deg[dst[e]], 1);
}

__global__ __launch_bounds__(256) void scan_kernel(const int* __restrict__ deg,
                                                   int* __restrict__ rowptr,
                                                   int* __restrict__ cursor) {
    __shared__ int part[256];
    const int t = threadIdx.x;
    const int base = t * 40;
    int s = 0;
    for (int i = 0; i < 40; ++i) {
        int idx = base + i;
        if (idx < N_NODES) s += deg[idx];
    }
    part[t] = s;
    __syncthreads();
    for (int o = 1; o < 256; o <<= 1) {
        int v = (t >= o) ? part[t - o] : 0;
        __syncthreads();
        part[t] += v;
        __syncthreads();
    }
    int run = (t == 0) ? 0 : part[t - 1];
    for (int i = 0; i < 40; ++i) {
        int idx = base + i;
        if (idx < N_NODES) {
            int d = deg[idx];
            rowptr[idx] = run;
            cursor[idx] = run;
            run += d;
        } else if (idx == N_NODES) {
            rowptr[idx] = run;
        }
    }
}

__global__ __launch_bounds__(256) void scatter_kernel(const int* __restrict__ dst,
                                                      int* __restrict__ cursor,
                                                      int* __restrict__ elist) {
    int e = blockIdx.x * 256 + threadIdx.x;
    if (e < N_EDGES) {
        int p = atomicAdd(&cursor[dst[e]], 1);
        elist[p] = e;
    }
}

// ---------------- prep: pack MLP weights into MFMA A-operand frags (swapped form) ----------------
// frag tile = 64 lanes x 16 B. Global tiles: [0,4)=W1 (mt), [4,12)=W2 (mt*2+kt), [12,36)=W3 (mt3*2+kt)
__global__ __launch_bounds__(64) void prep_frags(const float* __restrict__ Wfc1,
                                                 const float* __restrict__ Wfc2,
                                                 const float* __restrict__ Wfc3,
                                                 uint4* __restrict__ fragbuf) {
    const int tile = blockIdx.x;
    const int l = threadIdx.x;
    const int e = l & 15, g = l >> 4;
    unsigned p[4] = {0u, 0u, 0u, 0u};
    if (tile < 4) {
        // A = W1^T[64ch][8k pad 32]: lane holds row=16*mt+e, k=8g+j (zero for g>0)
        if (g == 0) {
            #pragma unroll
            for (int j = 0; j < 8; ++j) {
                unsigned short b = f2bf(Wfc1[j * 64 + tile * 16 + e]);
                p[j >> 1] |= (unsigned)b << (16 * (j & 1));
            }
        }
    } else if (tile < 12) {
        int t2 = tile - 4; int mt = t2 >> 1, kt = t2 & 1;
        #pragma unroll
        for (int j = 0; j < 8; ++j) {
            unsigned short b = f2bf(Wfc2[(kt * 32 + g * 8 + j) * 64 + mt * 16 + e]);
            p[j >> 1] |= (unsigned)b << (16 * (j & 1));
        }
    } else {
        int t3 = tile - 12; int mt3 = t3 >> 1, kt = t3 & 1;
        #pragma unroll
        for (int j = 0; j < 8; ++j) {
            unsigned short b = f2bf(Wfc3[(kt * 32 + g * 8 + j) * 192 + mt3 * 16 + e]);
            p[j >> 1] |= (unsigned)b << (16 * (j & 1));
        }
    }
    uint4 v; v.x = p[0]; v.y = p[1]; v.z = p[2]; v.w = p[3];
    fragbuf[tile * 64 + l] = v;
}

// ---------------- Kernel A: per-node linear1 (f_s, f_v) ----------------
__global__ __launch_bounds__(64) void node_l1_kernel(
    const float* __restrict__ node_input,
    const float* __restrict__ node_attr,
    const float* __restrict__ Wl1_0,
    const float* __restrict__ Wl1_1,
    float* __restrict__ f_s,
    float* __restrict__ f_v)
{
    const int n = blockIdx.x;
    const int t = threadIdx.x;
    __shared__ float x[160];
    const float* row = node_input + (size_t)n * 160;
    for (int i = t; i < 160; i += 64) x[i] = row[i];
    __syncthreads();
    const float a = node_attr[n];

    float acc = 0.f;
    for (int k = 0; k < 64; ++k) acc += x[k] * Wl1_0[k * 64 + t];
    f_s[(size_t)n * 64 + t] = acc * (a * 0.125f);

    const float sv = a * 0.17677669529663687f;
    for (int o = t; o < 96; o += 64) {
        int w = o / 3, c = o - w * 3;
        float av = 0.f;
        for (int u = 0; u < 32; ++u) av += x[64 + u * 3 + c] * Wl1_1[u * 32 + w];
        f_v[(size_t)n * 96 + o] = av * sv;
    }
}

// ---------------- Kernel B: MFMA MLP + TP + segmented scatter ----------------
#define SEGSTEP(v, a, m) { float u_ = __int_as_float(__builtin_amdgcn_ds_bpermute((a), __float_as_int(v))); (v) += u_ * (m); }
#define SEGSCAN(v) { SEGSTEP(v, a1, m1) SEGSTEP(v, a2, m2) SEGSTEP(v, a4, m4) SEGSTEP(v, a8, m8) SEGSTEP(v, a16, m16) SEGSTEP(v, a32, m32) }

// compute 16-channel w chunk (channels 16*mt3 .. +15) for this lane's own edge, into w16[]
#define W16CHUNK(mt3_, w16_) { \
    short8 a0_ = ((short8*)w3buf)[((mt3_) * 2 + 0) * 64 + l]; \
    short8 a1_ = ((short8*)w3buf)[((mt3_) * 2 + 1) * 64 + l]; \
    _Pragma("unroll") \
    for (int tt_ = 0; tt_ < 4; ++tt_) { \
        f32x4 d_ = {0.f, 0.f, 0.f, 0.f}; \
        d_ = __builtin_amdgcn_mfma_f32_16x16x32_bf16(a0_, bh2[2 * tt_], d_, 0, 0, 0); \
        d_ = __builtin_amdgcn_mfma_f32_16x16x32_bf16(a1_, bh2[2 * tt_ + 1], d_, 0, 0, 0); \
        *(f32x4*)(wb + (tt_ * 16 + er) * 80 + gr * 16) = d_; \
    } \
    _Pragma("unroll") \
    for (int q_ = 0; q_ < 4; ++q_) { \
        float4 v_ = *(float4*)(wb + l * 80 + q_ * 16); \
        w16_[q_ * 4 + 0] = v_.x; w16_[q_ * 4 + 1] = v_.y; \
        w16_[q_ * 4 + 2] = v_.z; w16_[q_ * 4 + 3] = v_.w; } }

__global__ __launch_bounds__(256) __attribute__((amdgpu_waves_per_eu(2, 2)))
void edge_kernel(
    const float* __restrict__ edge_attr,   // [E][4]
    const float* __restrict__ esa,         // [E][8]
    const float* __restrict__ f_s,         // [N][64]
    const float* __restrict__ f_v,         // [N][96]
    const int* __restrict__ edge_src,
    const int* __restrict__ edge_dst,
    const int* __restrict__ elist,         // dst-sorted edge ids
    const float4* __restrict__ fragbuf,    // packed weight frags (36 tiles)
    float* __restrict__ mid)               // [N][384], pre-zeroed
{
    // uni: [0,4096) xs staging / [4096,8192) w1 frags / [8192,16384) w2 frags  (phase A)
    //      reused as wbuf (4 waves x 5120 B)                                    (phase B)
    __shared__ __align__(16) char uni[20480];
    __shared__ __align__(16) char albuf[32768];   // 16 tiles x [16 e][64 ch] bf16, XOR-swizzled
    __shared__ __align__(16) char w3buf[24576];   // 24 W3 frag tiles

    const int tid = threadIdx.x;
    const int l = tid & 63;
    const int wid = tid >> 6;

    // ---- stage weight frags to LDS ----
    {
        float4* u1 = (float4*)(uni + 4096);
        u1[tid] = fragbuf[tid];
        float4* u2 = (float4*)(uni + 8192);
        u2[tid] = fragbuf[256 + tid];
        u2[tid + 256] = fragbuf[512 + tid];
        float4* u3 = (float4*)w3buf;
        #pragma unroll
        for (int i = 0; i < 6; ++i) u3[tid + 256 * i] = fragbuf[768 + tid + 256 * i];
    }

    const int s = blockIdx.x * 256 + tid;
    const int e = elist[s];

    // esa -> bf16 xs staging (B-operand rows for L1)
    {
        float4 xa = ((const float4*)esa)[e * 2 + 0];
        float4 xb = ((const float4*)esa)[e * 2 + 1];
        uint4 v;
        v.x = pk2(f2bf(xa.x), f2bf(xa.y));
        v.y = pk2(f2bf(xa.z), f2bf(xa.w));
        v.z = pk2(f2bf(xb.x), f2bf(xb.y));
        v.w = pk2(f2bf(xb.z), f2bf(xb.w));
        ((uint4*)uni)[tid] = v;
    }

    const int src = edge_src[e];
    const int mydst = edge_dst[e];
    float4 ea = ((const float4*)edge_attr)[e];
    const float y0 = ea.x, y1a = ea.y, y1b = ea.z, y1c = ea.w;

    // ---- segment info (edges sorted by dst) ----
    int up = __shfl_up(mydst, 1);
    bool is_head = (l == 0) || (up != mydst);
    int dn = __shfl_down(mydst, 1);
    const bool is_tail = (l == 63) || (dn != mydst);
    unsigned long long hb = __ballot(is_head);
    unsigned long long lowmask = (~0ull) >> (63 - l);
    int H = 63 - __clzll(hb & lowmask);
    int dist = l - H;
    const float m1  = dist >= 1  ? 1.f : 0.f;
    const float m2  = dist >= 2  ? 1.f : 0.f;
    const float m4  = dist >= 4  ? 1.f : 0.f;
    const float m8  = dist >= 8  ? 1.f : 0.f;
    const float m16 = dist >= 16 ? 1.f : 0.f;
    const float m32 = dist >= 32 ? 1.f : 0.f;
    const int a1  = ((l - 1)  & 63) * 4;
    const int a2  = ((l - 2)  & 63) * 4;
    const int a4  = ((l - 4)  & 63) * 4;
    const int a8  = ((l - 8)  & 63) * 4;
    const int a16 = ((l - 16) & 63) * 4;
    const int a32 = ((l - 32) & 63) * 4;

    __syncthreads();

    const int er = l & 15, gr = l >> 4;
    const int swz = (er & 7) << 4;

    // w2 frags resident (8 x 16B = 32 VGPR)
    short8 w2f[8];
    #pragma unroll
    for (int i = 0; i < 8; ++i) w2f[i] = ((short8*)(uni + 8192))[i * 64 + l];

    // ---- phase A: L1 + L2 per tile; h1/h2 in albuf (in-place) ----
    #pragma unroll 1
    for (int tt = 0; tt < 4; ++tt) {
        const int T = wid * 4 + tt;
        char* al = albuf + T * 2048;
        short8 bx = {0, 0, 0, 0, 0, 0, 0, 0};
        if (l < 16) bx = ((short8*)uni)[T * 16 + l];
        #pragma unroll
        for (int mt = 0; mt < 4; ++mt) {
            short8 aw = ((short8*)(uni + 4096))[mt * 64 + l];
            f32x4 c = {0.f, 0.f, 0.f, 0.f};
            c = __builtin_amdgcn_mfma_f32_16x16x32_bf16(aw, bx, c, 0, 0, 0);
            unsigned pa = pk2(f2bf(gelu_f(c[0] * 0.35355339059327373f)),
                              f2bf(gelu_f(c[1] * 0.35355339059327373f)));
            unsigned pb = pk2(f2bf(gelu_f(c[2] * 0.35355339059327373f)),
                              f2bf(gelu_f(c[3] * 0.35355339059327373f)));
            uint2 pv; pv.x = pa; pv.y = pb;
            *(uint2*)(al + ((er * 128 + mt * 32 + gr * 8) ^ swz)) = pv;
        }
        // L2: read h1 B-frags, then overwrite in place with h2
        short8 b0 = *(short8*)(al + ((er * 128 + 0  + gr * 16) ^ swz));
        short8 b1 = *(short8*)(al + ((er * 128 + 64 + gr * 16) ^ swz));
        #pragma unroll
        for (int mt = 0; mt < 4; ++mt) {
            f32x4 c = {0.f, 0.f, 0.f, 0.f};
            c = __builtin_amdgcn_mfma_f32_16x16x32_bf16(w2f[2 * mt + 0], b0, c, 0, 0, 0);
            c = __builtin_amdgcn_mfma_f32_16x16x32_bf16(w2f[2 * mt + 1], b1, c, 0, 0, 0);
            unsigned pa = pk2(f2bf(gelu_f(c[0] * 0.125f)), f2bf(gelu_f(c[1] * 0.125f)));
            unsigned pb = pk2(f2bf(gelu_f(c[2] * 0.125f)), f2bf(gelu_f(c[3] * 0.125f)));
            uint2 pv; pv.x = pa; pv.y = pb;
            *(uint2*)(al + ((er * 128 + mt * 32 + gr * 8) ^ swz)) = pv;
        }
    }

    __syncthreads();   // protects uni reuse as wbuf

    // ---- phase B: L3 MFMA per 16-ch chunk + TP + segscan + tail atomics ----
    short8 bh2[8];
    #pragma unroll
    for (int tt = 0; tt < 4; ++tt) {
        char* al = albuf + (wid * 4 + tt) * 2048;
        bh2[2 * tt + 0] = *(short8*)(al + ((er * 128 + 0  + gr * 16) ^ swz));
        bh2[2 * tt + 1] = *(short8*)(al + ((er * 128 + 64 + gr * 16) ^ swz));
    }
    char* wb = uni + wid * 5120;
    const float* gsrow = f_s + (size_t)src * 64;
    const float* gvrow = f_v + (size_t)src * 96;
    float* md = mid + (size_t)mydst * 384;

    #pragma unroll 1
    for (int jg = 0; jg < 4; ++jg) {
        float wA[16]; W16CHUNK(jg, wA);
        float wB[16]; W16CHUNK(jg + 4, wB);
        float gs16[16];
        #pragma unroll
        for (int q = 0; q < 4; ++q) {
            float4 g = ((const float4*)(gsrow + jg * 16))[q];
            gs16[q * 4 + 0] = g.x; gs16[q * 4 + 1] = g.y;
            gs16[q * 4 + 2] = g.z; gs16[q * 4 + 3] = g.w;
        }
        // PASS A: mid[0:64]
        {
            float acc[16];
            #pragma unroll
            for (int i = 0; i < 16; ++i) {
                acc[i] = 0.125f * wA[i] * gs16[i] * y0;
                SEGSCAN(acc[i]);
            }
            if (is_tail) {
                #pragma unroll
                for (int i = 0; i < 16; ++i) atomicAdd(md + jg * 16 + i, acc[i]);
            }
        }
        // PASS B: mid[96 + u*3 + c]
        {
            float acc[16], vb[16], vc[16];
            #pragma unroll
            for (int i = 0; i < 16; ++i) {
                float t_ = 0.125f * wB[i] * gs16[i];
                acc[i] = t_ * y1a; vb[i] = t_ * y1b; vc[i] = t_ * y1c;
                SEGSCAN(acc[i]);
            }
            #pragma unroll
            for (int i = 0; i < 16; ++i) { SEGSCAN(vb[i]); }
            #pragma unroll
            for (int i = 0; i < 16; ++i) { SEGSCAN(vc[i]); }
            if (is_tail) {
                #pragma unroll
                for (int i = 0; i < 16; ++i) {
                    int u = jg * 16 + i;
                    atomicAdd(md + 96 + u * 3 + 0, acc[i]);
                    atomicAdd(md + 96 + u * 3 + 1, vb[i]);
                    atomicAdd(md + 96 + u * 3 + 2, vc[i]);
                }
            }
        }
    }

    #pragma unroll 1
    for (int jv = 0; jv < 2; ++jv) {
        float wC[16]; W16CHUNK(8 + jv, wC);
        float wD[16]; W16CHUNK(10 + jv, wD);
        float gv48[48];
        #pragma unroll
        for (int q = 0; q < 12; ++q) {
            float4 g = ((const float4*)(gvrow + jv * 48))[q];
            gv48[q * 4 + 0] = g.x; gv48[q * 4 + 1] = g.y;
            gv48[q * 4 + 2] = g.z; gv48[q * 4 + 3] = g.w;
        }
        // PASS C: mid[288 + u*3 + c]
        {
            float acc[16], vb[16], vc[16];
            #pragma unroll
            for (int i = 0; i < 16; ++i) {
                float w2v = 0.125f * wC[i] * y0;
                acc[i] = w2v * gv48[3 * i + 0];
                vb[i]  = w2v * gv48[3 * i + 1];
                vc[i]  = w2v * gv48[3 * i + 2];
                SEGSCAN(acc[i]);
            }
            #pragma unroll
            for (int i = 0; i < 16; ++i) { SEGSCAN(vb[i]); }
            #pragma unroll
            for (int i = 0; i < 16; ++i) { SEGSCAN(vc[i]); }
            if (is_tail) {
                #pragma unroll
                for (int i = 0; i < 16; ++i) {
                    int u = jv * 16 + i;
                    atomicAdd(md + 288 + u * 3 + 0, acc[i]);
                    atomicAdd(md + 288 + u * 3 + 1, vb[i]);
                    atomicAdd(md + 288 + u * 3 + 2, vc[i]);
                }
            }
        }
        // PASS D: mid[64 + u]
        {
            float acc[16];
            #pragma unroll
            for (int i = 0; i < 16; ++i) {
                float dot = gv48[3 * i + 0] * y1a + gv48[3 * i + 1] * y1b + gv48[3 * i + 2] * y1c;
                acc[i] = 0.125f * wD[i] * dot * INV3;
                SEGSCAN(acc[i]);
            }
            if (is_tail) {
                #pragma unroll
                for (int i = 0; i < 16; ++i) atomicAdd(md + 64 + jv * 16 + i, acc[i]);
            }
        }
    }
}

// ---------------- Kernel C: per-node linear2 + gate + self-connection ----------------
__global__ __launch_bounds__(64) void node_out_kernel(
    const float* __restrict__ node_input,
    const float* __restrict__ node_attr,
    const float* __restrict__ Wsc0,
    const float* __restrict__ Wsc1,
    const float* __restrict__ Wl2_s,
    const float* __restrict__ Wl2_v,
    const float* __restrict__ Wa,
    const float* __restrict__ mid,
    float* __restrict__ out)
{
    const int n = blockIdx.x;
    const int t = threadIdx.x;
    __shared__ float x[160];
    __shared__ float m[384];
    const float inv = 0.17677669529663687f;  // 1/sqrt(NUM_NEIGHBORS)
    const float* row = node_input + (size_t)n * 160;
    for (int i = t; i < 160; i += 64) x[i] = row[i];
    for (int i = t; i < 384; i += 64) m[i] = mid[(size_t)n * 384 + i] * inv;
    __syncthreads();

    const float a = node_attr[n];
    const float s96 = a * 0.10206207261596575f;

    float alpha = 0.f;
    for (int i = 0; i < 96; ++i) alpha += m[i] * Wa[i];
    alpha *= s96;

    float outs = 0.f;
    for (int i = 0; i < 96; ++i) outs += m[i] * Wl2_s[i * 64 + t];
    outs *= s96;
    float scs = 0.f;
    for (int k = 0; k < 64; ++k) scs += x[k] * Wsc0[k * 64 + t];
    scs *= a * 0.125f;
    out[(size_t)n * 160 + t] = scs + alpha * outs;

    const float sv = a * 0.17677669529663687f;
    for (int o = t; o < 96; o += 64) {
        int w = o / 3, c = o - w * 3;
        float ov = 0.f;
        for (int u = 0; u < 64; ++u) ov += m[96 + u * 3 + c] * Wl2_v[u * 32 + w];
        for (int u = 0; u < 32; ++u) ov += m[288 + u * 3 + c] * Wl2_v[(64 + u) * 32 + w];
        ov *= s96;
        float scv = 0.f;
        for (int u = 0; u < 32; ++u) scv += x[64 + u * 3 + c] * Wsc1[u * 32 + w];
        scv *= sv;
        out[(size_t)n * 160 + 64 + o] = scv + alpha * ov;
    }
}

extern "C" void kernel_launch(void* const* d_in, const int* in_sizes, int n_in,
                              void* d_out, int out_size, void* d_ws, size_t ws_size,
                              hipStream_t stream) {
    const float* node_input = (const float*)d_in[0];
    const float* node_attr  = (const float*)d_in[1];
    const float* edge_attr  = (const float*)d_in[2];
    const float* esa        = (const float*)d_in[3];
    const float* Wsc0       = (const float*)d_in[4];
    const float* Wsc1       = (const float*)d_in[5];
    const float* Wl1_0      = (const float*)d_in[6];
    const float* Wl1_1      = (const float*)d_in[7];
    const float* Wfc1       = (const float*)d_in[8];
    const float* Wfc2       = (const float*)d_in[9];
    const float* Wfc3       = (const float*)d_in[10];
    const float* Wl2_s      = (const float*)d_in[11];
    const float* Wl2_v      = (const float*)d_in[12];
    const float* Wa         = (const float*)d_in[13];
    const int* edge_src     = (const int*)d_in[14];
    const int* edge_dst     = (const int*)d_in[15];
    float* out = (float*)d_out;

    float* ws  = (float*)d_ws;
    float* f_s = ws;                          // N*64
    float* f_v = ws + (size_t)N_NODES * 64;   // N*96
    float* mid = ws + (size_t)N_NODES * 160;  // N*384

    // scratch in d_out (dead until node_out_kernel overwrites it)
    int* ibuf   = (int*)d_out;
    int* deg    = ibuf;            // 10000
    int* rowptr = ibuf + 10016;    // 10001
    int* cursor = ibuf + 20032;    // 10000
    int* elist  = ibuf + 30080;    // 320000 -> ends 350080
    uint4* fragbuf = (uint4*)((float*)d_out + 400000);  // 36*64*16B = 36 KB, ends well < 1.6M floats

    hipMemsetAsync(deg, 0, (size_t)N_NODES * sizeof(int), stream);
    hipMemsetAsync(mid, 0, (size_t)N_NODES * 384 * sizeof(float), stream);

    hist_kernel<<<(N_EDGES + 255) / 256, 256, 0, stream>>>(edge_dst, deg);
    scan_kernel<<<1, 256, 0, stream>>>(deg, rowptr, cursor);
    scatter_kernel<<<(N_EDGES + 255) / 256, 256, 0, stream>>>(edge_dst, cursor, elist);
    prep_frags<<<36, 64, 0, stream>>>(Wfc1, Wfc2, Wfc3, fragbuf);

    node_l1_kernel<<<N_NODES, 64, 0, stream>>>(node_input, node_attr, Wl1_0, Wl1_1, f_s, f_v);
    edge_kernel<<<N_EDGES / 256, 256, 0, stream>>>(edge_attr, esa, f_s, f_v,
                                                   edge_src, edge_dst, elist,
                                                   (const float4*)fragbuf, mid);
    node_out_kernel<<<N_NODES, 64, 0, stream>>>(node_input, node_attr, Wsc0, Wsc1,
                                                Wl2_s, Wl2_v, Wa, mid, out);
}

// Round 5
// 275.970 us; speedup vs baseline: 2.6023x; 1.9038x over previous
//
#include <hip/hip_runtime.h>

#define N_NODES 10000
#define N_EDGES 320000
#define INV3 0.5773502691896258f

typedef short short8 __attribute__((ext_vector_type(8)));
typedef float f32x4 __attribute__((ext_vector_type(4)));

__device__ __forceinline__ float gelu_f(float x) {
    float x3 = x * x * x;
    return x / (1.0f + __expf(-1.5957691216057308f * (x + 0.044715f * x3)));
}

__device__ __forceinline__ unsigned short f2bf(float f) {
    unsigned u = __float_as_uint(f);
    unsigned r = (u + 0x7FFFu + ((u >> 16) & 1u)) >> 16;
    return (unsigned short)r;
}
__device__ __forceinline__ unsigned pk2(unsigned short lo, unsigned short hi) {
    return (unsigned)lo | ((unsigned)hi << 16);
}

// sum over the 16-lane row; result valid in lane 15 of each row (VALU DPP, no LDS)
__device__ __forceinline__ float rowsum16(float v) {
    v += __int_as_float(__builtin_amdgcn_update_dpp(0, __float_as_int(v), 0x118, 0xf, 0xf, true));
    v += __int_as_float(__builtin_amdgcn_update_dpp(0, __float_as_int(v), 0x114, 0xf, 0xf, true));
    v += __int_as_float(__builtin_amdgcn_update_dpp(0, __float_as_int(v), 0x112, 0xf, 0xf, true));
    v += __int_as_float(__builtin_amdgcn_update_dpp(0, __float_as_int(v), 0x111, 0xf, 0xf, true));
    return v;
}

// ---------------- CSR build ----------------
__global__ __launch_bounds__(256) void hist_kernel(const int* __restrict__ dst, int* __restrict__ deg) {
    int e = blockIdx.x * 256 + threadIdx.x;
    if (e < N_EDGES) atomicAdd(&deg[dst[e]], 1);
}

__global__ __launch_bounds__(256) void scan_kernel(const int* __restrict__ deg,
                                                   int* __restrict__ rowptr,
                                                   int* __restrict__ cursor) {
    __shared__ int part[256];
    const int t = threadIdx.x;
    const int base = t * 40;
    int s = 0;
    for (int i = 0; i < 40; ++i) {
        int idx = base + i;
        if (idx < N_NODES) s += deg[idx];
    }
    part[t] = s;
    __syncthreads();
    for (int o = 1; o < 256; o <<= 1) {
        int v = (t >= o) ? part[t - o] : 0;
        __syncthreads();
        part[t] += v;
        __syncthreads();
    }
    int run = (t == 0) ? 0 : part[t - 1];
    for (int i = 0; i < 40; ++i) {
        int idx = base + i;
        if (idx < N_NODES) {
            int d = deg[idx];
            rowptr[idx] = run;
            cursor[idx] = run;
            run += d;
        } else if (idx == N_NODES) {
            rowptr[idx] = run;
        }
    }
}

__global__ __launch_bounds__(256) void scatter_kernel(const int* __restrict__ dst,
                                                      int* __restrict__ cursor,
                                                      int* __restrict__ elist) {
    int e = blockIdx.x * 256 + threadIdx.x;
    if (e < N_EDGES) {
        int p = atomicAdd(&cursor[dst[e]], 1);
        elist[p] = e;
    }
}

// ---------------- prep: pack MLP weights into MFMA A-operand frags ----------------
// tiles: [0,4)=W1 (mt), [4,12)=W2 (mt*2+kt), [12,36)=W3 (mt3*2+kt)
__global__ __launch_bounds__(64) void prep_frags(const float* __restrict__ Wfc1,
                                                 const float* __restrict__ Wfc2,
                                                 const float* __restrict__ Wfc3,
                                                 uint4* __restrict__ fragbuf) {
    const int tile = blockIdx.x;
    const int l = threadIdx.x;
    const int e = l & 15, g = l >> 4;
    unsigned p[4] = {0u, 0u, 0u, 0u};
    if (tile < 4) {
        if (g == 0) {
            #pragma unroll
            for (int j = 0; j < 8; ++j) {
                unsigned short b = f2bf(Wfc1[j * 64 + tile * 16 + e]);
                p[j >> 1] |= (unsigned)b << (16 * (j & 1));
            }
        }
    } else if (tile < 12) {
        int t2 = tile - 4; int mt = t2 >> 1, kt = t2 & 1;
        #pragma unroll
        for (int j = 0; j < 8; ++j) {
            unsigned short b = f2bf(Wfc2[(kt * 32 + g * 8 + j) * 64 + mt * 16 + e]);
            p[j >> 1] |= (unsigned)b << (16 * (j & 1));
        }
    } else {
        int t3 = tile - 12; int mt3 = t3 >> 1, kt = t3 & 1;
        #pragma unroll
        for (int j = 0; j < 8; ++j) {
            unsigned short b = f2bf(Wfc3[(kt * 32 + g * 8 + j) * 192 + mt3 * 16 + e]);
            p[j >> 1] |= (unsigned)b << (16 * (j & 1));
        }
    }
    uint4 v; v.x = p[0]; v.y = p[1]; v.z = p[2]; v.w = p[3];
    fragbuf[tile * 64 + l] = v;
}

// ---------------- Kernel A: per-node linear1 (f_s, f_v) ----------------
__global__ __launch_bounds__(64) void node_l1_kernel(
    const float* __restrict__ node_input,
    const float* __restrict__ node_attr,
    const float* __restrict__ Wl1_0,
    const float* __restrict__ Wl1_1,
    float* __restrict__ f_s,
    float* __restrict__ f_v)
{
    const int n = blockIdx.x;
    const int t = threadIdx.x;
    __shared__ float x[160];
    const float* row = node_input + (size_t)n * 160;
    for (int i = t; i < 160; i += 64) x[i] = row[i];
    __syncthreads();
    const float a = node_attr[n];

    float acc = 0.f;
    for (int k = 0; k < 64; ++k) acc += x[k] * Wl1_0[k * 64 + t];
    f_s[(size_t)n * 64 + t] = acc * (a * 0.125f);

    const float sv = a * 0.17677669529663687f;
    for (int o = t; o < 96; o += 64) {
        int w = o / 3, c = o - w * 3;
        float av = 0.f;
        for (int u = 0; u < 32; ++u) av += x[64 + u * 3 + c] * Wl1_1[u * 32 + w];
        f_v[(size_t)n * 96 + o] = av * sv;
    }
}

// ---------------- fused node-centric kernel: one wave per dst node ----------------
#define L3CHUNK(mt3_, d_) { \
    short8 a0_ = ((short8*)wfrag)[(12 + (mt3_) * 2 + 0) * 64 + l]; \
    short8 a1_ = ((short8*)wfrag)[(12 + (mt3_) * 2 + 1) * 64 + l]; \
    d_[0] = 0.f; d_[1] = 0.f; d_[2] = 0.f; d_[3] = 0.f; \
    d_ = __builtin_amdgcn_mfma_f32_16x16x32_bf16(a0_, bh0, d_, 0, 0, 0); \
    d_ = __builtin_amdgcn_mfma_f32_16x16x32_bf16(a1_, bh1, d_, 0, 0, 0); }

__global__ __launch_bounds__(256) __attribute__((amdgpu_waves_per_eu(2, 2)))
void fused_kernel(
    const float* __restrict__ edge_attr,   // [E][4]
    const float* __restrict__ esa,         // [E][8]
    const float* __restrict__ f_s,         // [N][64]
    const float* __restrict__ f_v,         // [N][96]
    const int* __restrict__ edge_src,
    const int* __restrict__ elist,         // dst-sorted edge ids
    const int* __restrict__ rowptr,        // [N+1]
    const float4* __restrict__ fragbuf,    // 36 weight frag tiles
    const float* __restrict__ node_input,
    const float* __restrict__ node_attr,
    const float* __restrict__ Wsc0,
    const float* __restrict__ Wsc1,
    const float* __restrict__ Wl2_s,
    const float* __restrict__ Wl2_v,
    const float* __restrict__ Wa,
    float* __restrict__ out)
{
    __shared__ __align__(16) char wfrag[36864];   // all MLP weight frags
    __shared__ __align__(16) char albuf[4 * 2048];
    __shared__ __align__(16) float mld[4][384];
    __shared__ __align__(16) float xld[4][160];

    const int tid = threadIdx.x;
    const int l = tid & 63;
    const int wid = tid >> 6;

    {
        float4* w = (float4*)wfrag;
        #pragma unroll
        for (int i = 0; i < 9; ++i) w[tid + 256 * i] = fragbuf[tid + 256 * i];
    }

    const int n = blockIdx.x * 4 + wid;    // dst node (grid = 2500 blocks)
    const int p0 = rowptr[n], p1 = rowptr[n + 1];

    for (int i = l; i < 160; i += 64) xld[wid][i] = node_input[(size_t)n * 160 + i];

    __syncthreads();

    const int er = l & 15, gr = l >> 4;
    const int swz = (er & 7) << 4;
    char* al = albuf + wid * 2048;

    short8 w2f[8];
    #pragma unroll
    for (int i = 0; i < 8; ++i) w2f[i] = ((short8*)(wfrag + 4096))[i * 64 + l];

    float acc0[4][4];     // w0 -> mid_s[0:64]
    float acc1[2][4];     // w3 -> mid_s[64:96]
    float acc2[4][4][3];  // w1 -> mid_v[0:64]
    float acc3[2][4][3];  // w2 -> mid_v[64:96]
    #pragma unroll
    for (int jg = 0; jg < 4; ++jg)
        #pragma unroll
        for (int r = 0; r < 4; ++r) {
            acc0[jg][r] = 0.f;
            acc2[jg][r][0] = 0.f; acc2[jg][r][1] = 0.f; acc2[jg][r][2] = 0.f;
        }
    #pragma unroll
    for (int jv = 0; jv < 2; ++jv)
        #pragma unroll
        for (int r = 0; r < 4; ++r) {
            acc1[jv][r] = 0.f;
            acc3[jv][r][0] = 0.f; acc3[jv][r][1] = 0.f; acc3[jv][r][2] = 0.f;
        }

    #pragma unroll 1
    for (int p = p0; p < p1; p += 16) {
        // my column's edge (clamped to a valid dummy; contributions are 0 via w=0)
        const int ci = p + er;
        const bool cval = ci < p1;
        const int ec = elist[cval ? ci : p0];
        const float4 ea = ((const float4*)edge_attr)[ec];
        const float y0 = ea.x, y1a = ea.y, y1b = ea.z, y1c = ea.w;
        const int src = edge_src[ec];

        // L1 B operand: lanes 0..15 hold col=l, k=0..7
        short8 bx = {0, 0, 0, 0, 0, 0, 0, 0};
        if (l < 16 && cval) {
            float4 xa = ((const float4*)esa)[(size_t)ec * 2 + 0];
            float4 xb = ((const float4*)esa)[(size_t)ec * 2 + 1];
            union { uint4 u; short8 s; } uv;
            uv.u.x = pk2(f2bf(xa.x), f2bf(xa.y));
            uv.u.y = pk2(f2bf(xa.z), f2bf(xa.w));
            uv.u.z = pk2(f2bf(xb.x), f2bf(xb.y));
            uv.u.w = pk2(f2bf(xb.z), f2bf(xb.w));
            bx = uv.s;
        }

        // ---- L1 ----
        #pragma unroll
        for (int mt = 0; mt < 4; ++mt) {
            short8 aw = ((short8*)wfrag)[mt * 64 + l];
            f32x4 c = {0.f, 0.f, 0.f, 0.f};
            c = __builtin_amdgcn_mfma_f32_16x16x32_bf16(aw, bx, c, 0, 0, 0);
            unsigned pa = pk2(f2bf(gelu_f(c[0] * 0.35355339059327373f)),
                              f2bf(gelu_f(c[1] * 0.35355339059327373f)));
            unsigned pb = pk2(f2bf(gelu_f(c[2] * 0.35355339059327373f)),
                              f2bf(gelu_f(c[3] * 0.35355339059327373f)));
            uint2 pv; pv.x = pa; pv.y = pb;
            *(uint2*)(al + ((er * 128 + mt * 32 + gr * 8) ^ swz)) = pv;
        }
        // ---- L2 ----
        {
            short8 b0 = *(short8*)(al + ((er * 128 + 0  + gr * 16) ^ swz));
            short8 b1 = *(short8*)(al + ((er * 128 + 64 + gr * 16) ^ swz));
            #pragma unroll
            for (int mt = 0; mt < 4; ++mt) {
                f32x4 c = {0.f, 0.f, 0.f, 0.f};
                c = __builtin_amdgcn_mfma_f32_16x16x32_bf16(w2f[2 * mt + 0], b0, c, 0, 0, 0);
                c = __builtin_amdgcn_mfma_f32_16x16x32_bf16(w2f[2 * mt + 1], b1, c, 0, 0, 0);
                unsigned pa = pk2(f2bf(gelu_f(c[0] * 0.125f)), f2bf(gelu_f(c[1] * 0.125f)));
                unsigned pb = pk2(f2bf(gelu_f(c[2] * 0.125f)), f2bf(gelu_f(c[3] * 0.125f)));
                uint2 pv; pv.x = pa; pv.y = pb;
                *(uint2*)(al + ((er * 128 + mt * 32 + gr * 8) ^ swz)) = pv;
            }
        }
        short8 bh0 = *(short8*)(al + ((er * 128 + 0  + gr * 16) ^ swz));
        short8 bh1 = *(short8*)(al + ((er * 128 + 64 + gr * 16) ^ swz));

        // ---- L3 + TP in D-layout (lane: 4 channels x its edge col) ----
        #pragma unroll
        for (int jg = 0; jg < 4; ++jg) {
            f32x4 gs4 = *(const f32x4*)(f_s + (size_t)src * 64 + jg * 16 + gr * 4);
            f32x4 dA; L3CHUNK(jg, dA);
            f32x4 dB; L3CHUNK(jg + 4, dB);
            #pragma unroll
            for (int r = 0; r < 4; ++r) {
                acc0[jg][r] += 0.125f * dA[r] * gs4[r] * y0;
                float t_ = 0.125f * dB[r] * gs4[r];
                acc2[jg][r][0] += t_ * y1a;
                acc2[jg][r][1] += t_ * y1b;
                acc2[jg][r][2] += t_ * y1c;
            }
        }
        #pragma unroll
        for (int jv = 0; jv < 2; ++jv) {
            const f32x4* gp = (const f32x4*)(f_v + (size_t)src * 96 + (size_t)(jv * 16 + gr * 4) * 3);
            f32x4 g0 = gp[0], g1 = gp[1], g2 = gp[2];
            float gv[12] = {g0[0], g0[1], g0[2], g0[3],
                            g1[0], g1[1], g1[2], g1[3],
                            g2[0], g2[1], g2[2], g2[3]};
            f32x4 dC; L3CHUNK(8 + jv, dC);
            f32x4 dD; L3CHUNK(10 + jv, dD);
            #pragma unroll
            for (int r = 0; r < 4; ++r) {
                float w2v = 0.125f * dC[r] * y0;
                acc3[jv][r][0] += w2v * gv[r * 3 + 0];
                acc3[jv][r][1] += w2v * gv[r * 3 + 1];
                acc3[jv][r][2] += w2v * gv[r * 3 + 2];
                float dot = gv[r * 3 + 0] * y1a + gv[r * 3 + 1] * y1b + gv[r * 3 + 2] * y1c;
                acc1[jv][r] += 0.125f * dD[r] * dot * INV3;
            }
        }
    }

    // ---- column reduce (DPP, VALU-only); lane er==15 holds sums ----
    #pragma unroll
    for (int jg = 0; jg < 4; ++jg)
        #pragma unroll
        for (int r = 0; r < 4; ++r) {
            acc0[jg][r] = rowsum16(acc0[jg][r]);
            acc2[jg][r][0] = rowsum16(acc2[jg][r][0]);
            acc2[jg][r][1] = rowsum16(acc2[jg][r][1]);
            acc2[jg][r][2] = rowsum16(acc2[jg][r][2]);
        }
    #pragma unroll
    for (int jv = 0; jv < 2; ++jv)
        #pragma unroll
        for (int r = 0; r < 4; ++r) {
            acc1[jv][r] = rowsum16(acc1[jv][r]);
            acc3[jv][r][0] = rowsum16(acc3[jv][r][0]);
            acc3[jv][r][1] = rowsum16(acc3[jv][r][1]);
            acc3[jv][r][2] = rowsum16(acc3[jv][r][2]);
        }

    const float iN = 0.17677669529663687f;   // 1/sqrt(NUM_NEIGHBORS)
    if (er == 15) {
        float* m = mld[wid];
        #pragma unroll
        for (int jg = 0; jg < 4; ++jg) {
            f32x4 v;
            v[0] = acc0[jg][0] * iN; v[1] = acc0[jg][1] * iN;
            v[2] = acc0[jg][2] * iN; v[3] = acc0[jg][3] * iN;
            *(f32x4*)(m + jg * 16 + gr * 4) = v;
        }
        #pragma unroll
        for (int jv = 0; jv < 2; ++jv) {
            f32x4 v;
            v[0] = acc1[jv][0] * iN; v[1] = acc1[jv][1] * iN;
            v[2] = acc1[jv][2] * iN; v[3] = acc1[jv][3] * iN;
            *(f32x4*)(m + 64 + jv * 16 + gr * 4) = v;
        }
        #pragma unroll
        for (int jg = 0; jg < 4; ++jg) {
            float t[12];
            #pragma unroll
            for (int r = 0; r < 4; ++r) {
                t[r * 3 + 0] = acc2[jg][r][0] * iN;
                t[r * 3 + 1] = acc2[jg][r][1] * iN;
                t[r * 3 + 2] = acc2[jg][r][2] * iN;
            }
            float* b = m + 96 + (jg * 16 + gr * 4) * 3;
            *(f32x4*)(b + 0) = (f32x4){t[0], t[1], t[2], t[3]};
            *(f32x4*)(b + 4) = (f32x4){t[4], t[5], t[6], t[7]};
            *(f32x4*)(b + 8) = (f32x4){t[8], t[9], t[10], t[11]};
        }
        #pragma unroll
        for (int jv = 0; jv < 2; ++jv) {
            float t[12];
            #pragma unroll
            for (int r = 0; r < 4; ++r) {
                t[r * 3 + 0] = acc3[jv][r][0] * iN;
                t[r * 3 + 1] = acc3[jv][r][1] * iN;
                t[r * 3 + 2] = acc3[jv][r][2] * iN;
            }
            float* b = m + 288 + (jv * 16 + gr * 4) * 3;
            *(f32x4*)(b + 0) = (f32x4){t[0], t[1], t[2], t[3]};
            *(f32x4*)(b + 4) = (f32x4){t[4], t[5], t[6], t[7]};
            *(f32x4*)(b + 8) = (f32x4){t[8], t[9], t[10], t[11]};
        }
    }
    // within-wave LDS write->read is ordered by lgkmcnt; no barrier needed

    // ---- fused linear2 + gate + self-connection (per-wave node_out) ----
    const float a = node_attr[n];
    const float* m = mld[wid];
    const float* x = xld[wid];
    const float s96 = a * 0.10206207261596575f;

    float alpha = 0.f;
    for (int i = 0; i < 96; ++i) alpha += m[i] * Wa[i];
    alpha *= s96;

    float outs = 0.f;
    for (int i = 0; i < 96; ++i) outs += m[i] * Wl2_s[i * 64 + l];
    outs *= s96;
    float scs = 0.f;
    for (int k = 0; k < 64; ++k) scs += x[k] * Wsc0[k * 64 + l];
    scs *= a * 0.125f;
    out[(size_t)n * 160 + l] = scs + alpha * outs;

    const float sv = a * 0.17677669529663687f;
    for (int o = l; o < 96; o += 64) {
        int w = o / 3, c = o - w * 3;
        float ov = 0.f;
        for (int u = 0; u < 64; ++u) ov += m[96 + u * 3 + c] * Wl2_v[u * 32 + w];
        for (int u = 0; u < 32; ++u) ov += m[288 + u * 3 + c] * Wl2_v[(64 + u) * 32 + w];
        ov *= s96;
        float scv = 0.f;
        for (int u = 0; u < 32; ++u) scv += x[64 + u * 3 + c] * Wsc1[u * 32 + w];
        scv *= sv;
        out[(size_t)n * 160 + 64 + o] = scv + alpha * ov;
    }
}

extern "C" void kernel_launch(void* const* d_in, const int* in_sizes, int n_in,
                              void* d_out, int out_size, void* d_ws, size_t ws_size,
                              hipStream_t stream) {
    const float* node_input = (const float*)d_in[0];
    const float* node_attr  = (const float*)d_in[1];
    const float* edge_attr  = (const float*)d_in[2];
    const float* esa        = (const float*)d_in[3];
    const float* Wsc0       = (const float*)d_in[4];
    const float* Wsc1       = (const float*)d_in[5];
    const float* Wl1_0      = (const float*)d_in[6];
    const float* Wl1_1      = (const float*)d_in[7];
    const float* Wfc1       = (const float*)d_in[8];
    const float* Wfc2       = (const float*)d_in[9];
    const float* Wfc3       = (const float*)d_in[10];
    const float* Wl2_s      = (const float*)d_in[11];
    const float* Wl2_v      = (const float*)d_in[12];
    const float* Wa         = (const float*)d_in[13];
    const int* edge_src     = (const int*)d_in[14];
    const int* edge_dst     = (const int*)d_in[15];
    float* out = (float*)d_out;

    // ws layout (floats): f_s | f_v | fragbuf | int CSR scratch
    float* ws  = (float*)d_ws;
    float* f_s = ws;                              // N*64
    float* f_v = ws + (size_t)N_NODES * 64;       // N*96
    uint4* fragbuf = (uint4*)(ws + 1600000);      // 36*64 uint4 = 9216 floats
    int* ibuf   = (int*)(ws + 1609216);
    int* deg    = ibuf;            // 10000
    int* rowptr = ibuf + 10016;    // 10001
    int* cursor = ibuf + 20032;    // 10000
    int* elist  = ibuf + 30080;    // 320000

    hipMemsetAsync(deg, 0, (size_t)N_NODES * sizeof(int), stream);

    hist_kernel<<<(N_EDGES + 255) / 256, 256, 0, stream>>>(edge_dst, deg);
    scan_kernel<<<1, 256, 0, stream>>>(deg, rowptr, cursor);
    scatter_kernel<<<(N_EDGES + 255) / 256, 256, 0, stream>>>(edge_dst, cursor, elist);
    prep_frags<<<36, 64, 0, stream>>>(Wfc1, Wfc2, Wfc3, fragbuf);
    node_l1_kernel<<<N_NODES, 64, 0, stream>>>(node_input, node_attr, Wl1_0, Wl1_1, f_s, f_v);

    fused_kernel<<<N_NODES / 4, 256, 0, stream>>>(edge_attr, esa, f_s, f_v,
                                                  edge_src, elist, rowptr,
                                                  (const float4*)fragbuf,
                                                  node_input, node_attr,
                                                  Wsc0, Wsc1, Wl2_s, Wl2_v, Wa,
                                                  out);
}